// Round 5
// baseline (461.957 us; speedup 1.0000x reference)
//
#include <hip/hip_runtime.h>
#include <hip/hip_bf16.h>
#include <stdint.h>

// ERGCNConv on MI355X (gfx950).
// R7: eliminate the 205 MB hW intermediate. Edges sorted by (dst,et) via an 800K
//     pair-CSR scan; one fused kernel per 64-dst tile builds, per et, the A-row
//     bf16(inv * sum feats[src]) by gathering from the L2/L3-resident featsbf,
//     then MFMAs A@W_et accumulating across all 16 ets (inv folded into A).
//     Bias of present ets added in the epilogue. hw_gemm_k + agg_k deleted.
// Pipeline: memset | prep | hist | scanP1/2/3 (800K pair CSR + node-type offsets)
//           | scatter (edges -> (dst,et)-sorted src list; nodes -> ntype-sorted)
//           | fused_k (gather+segment-mean+16xMFMA -> agg)
//           | node gather-GEMM fused epilogue (+agg, bias, ReLU)

#define D 128
#define TRELS 16
#define NTYPES 8
#define DSTB 64   // dsts per fused block

typedef __bf16 bf16x8 __attribute__((ext_vector_type(8)));
typedef float f32x4 __attribute__((ext_vector_type(4)));
typedef unsigned int u32x4 __attribute__((ext_vector_type(4)));

__device__ __forceinline__ unsigned short f2bf(float f) {
  union { float f; unsigned u; } v; v.f = f;
  unsigned u = v.u;
  return (unsigned short)((u + 0x7FFFu + ((u >> 16) & 1u)) >> 16);  // RNE
}
// unpack 2 bf16 from a dword: lo = bits<<16, hi = bits&0xffff0000
__device__ __forceinline__ void bfpair(unsigned u, float& lo, float& hi) {
  union { unsigned u; float f; } a, b;
  a.u = u << 16; b.u = u & 0xffff0000u;
  lo = a.f; hi = b.f;
}

// ---------- prep: feats -> bf16; W_edge/W_node -> transposed bf16 [t][n][k] ----------
__global__ void prep_k(const float* __restrict__ feats,
                       const float* __restrict__ We,
                       const float* __restrict__ Wn,
                       unsigned short* __restrict__ featsbf,
                       unsigned short* __restrict__ WeT,
                       unsigned short* __restrict__ WnT,
                       int nfeat) {
  int idx = blockIdx.x * 256 + threadIdx.x;
  if (idx < nfeat) { featsbf[idx] = f2bf(feats[idx]); return; }
  idx -= nfeat;
  if (idx < TRELS * D * D) {
    int t = idx >> 14, rem = idx & 16383;
    int n = rem >> 7, k = rem & 127;
    WeT[idx] = f2bf(We[t * 16384 + k * 128 + n]);   // B^T layout: [n][k]
    return;
  }
  idx -= TRELS * D * D;
  if (idx < NTYPES * D * D) {
    int t = idx >> 14, rem = idx & 16383;
    int n = rem >> 7, k = rem & 127;
    WnT[idx] = f2bf(Wn[t * 16384 + k * 128 + n]);
  }
}

// ---------- hist: cnt[dst*16+et]++, node-type histogram ----------
__global__ void hist_k(const int* __restrict__ dst, const int* __restrict__ etypes,
                       const int* __restrict__ ntypes, int E, int N,
                       int* __restrict__ cnt, int* __restrict__ nhist) {
  __shared__ int sh_n[NTYPES];
  int tid = threadIdx.x;
  if (tid < NTYPES) sh_n[tid] = 0;
  __syncthreads();
  int g = blockIdx.x * 256 + tid;
  if (g < E) atomicAdd(&cnt[dst[g] * TRELS + etypes[g]], 1);
  if (g < N) atomicAdd(&sh_n[ntypes[g]], 1);
  __syncthreads();
  if (tid < NTYPES && sh_n[tid]) atomicAdd(&nhist[tid], sh_n[tid]);
}

// misc layout (ints): noff[0..8], ntb[9..17], ncur[18..25], nhist[26..33]
// ---------- scanP1: block-local exclusive scan over cnt[0..M) -> poff; block sums ----------
__global__ void scan1_k(const int* __restrict__ cnt, int* __restrict__ poff,
                        int* __restrict__ bsum, int M) {
  __shared__ int sd[256];
  int b = blockIdx.x, tid = threadIdx.x;
  int base = b * 1024 + tid * 4;
  int v[4]; int tot = 0;
  for (int j = 0; j < 4; ++j) {
    int i = base + j;
    int c = (i < M) ? cnt[i] : 0;
    v[j] = tot; tot += c;
  }
  sd[tid] = tot;
  __syncthreads();
  for (int off = 1; off < 256; off <<= 1) {
    int t = (tid >= off) ? sd[tid - off] : 0;
    __syncthreads();
    sd[tid] += t;
    __syncthreads();
  }
  int excl = sd[tid] - tot;
  for (int j = 0; j < 4; ++j) {
    int i = base + j;
    if (i < M) poff[i] = excl + v[j];
  }
  if (tid == 255) bsum[b] = sd[255];
}

// ---------- scanP2: scan block sums; node-type scan ----------
__global__ void scan2_k(int* __restrict__ misc, int* __restrict__ bsum, int nb) {
  if (threadIdx.x != 0) return;
  int run = 0;
  for (int b = 0; b < nb; ++b) { int t = bsum[b]; bsum[b] = run; run += t; }
  int* noff = misc; int* ntb = misc + 9; int* ncur = misc + 18; int* nhist = misc + 26;
  int s = 0, ts = 0;
  for (int t = 0; t < NTYPES; ++t) {
    noff[t] = s; ncur[t] = s; ntb[t] = ts;
    s += nhist[t]; ts += (nhist[t] + 127) >> 7;
  }
  noff[NTYPES] = s; ntb[NTYPES] = ts;
}

// ---------- scanP3: add block offsets; init pcur; poff[M] = E ----------
__global__ void scan3_k(int* __restrict__ poff, int* __restrict__ pcur,
                        const int* __restrict__ bsum, int M, int E) {
  int b = blockIdx.x, tid = threadIdx.x;
  int add = bsum[b];
  int base = b * 1024 + tid * 4;
  for (int j = 0; j < 4; ++j) {
    int i = base + j;
    if (i < M) { int o = poff[i] + add; poff[i] = o; pcur[i] = o; }
  }
  if (b == 0 && tid == 0) poff[M] = E;
}

// ---------- scatter: edges -> (dst,et)-sorted src list; nodes -> ntype-sorted ----------
__global__ void scatter_k(const int* __restrict__ src, const int* __restrict__ dst,
                          const int* __restrict__ etypes, const int* __restrict__ ntypes,
                          int E, int N, int* __restrict__ misc,
                          int* __restrict__ pcur,
                          int* __restrict__ esrc, int* __restrict__ nsorted) {
  __shared__ int lc_n[NTYPES], lb_n[NTYPES];
  int tid = threadIdx.x;
  if (tid < NTYPES) lc_n[tid] = 0;
  __syncthreads();
  int g = blockIdx.x * 256 + tid;
  if (g < E) {
    int key = dst[g] * TRELS + etypes[g];
    int pos = atomicAdd(&pcur[key], 1);
    esrc[pos] = src[g];
  }
  int tn = -1, idn = 0;
  if (g < N) { tn = ntypes[g]; idn = atomicAdd(&lc_n[tn], 1); }
  __syncthreads();
  if (tid < NTYPES && lc_n[tid]) lb_n[tid] = atomicAdd(&misc[18 + tid], lc_n[tid]);
  __syncthreads();
  if (g < N) nsorted[lb_n[tn] + idn] = g;
}

// ---------- fused: agg[d] = sum_et (mean feats[src over (d,et)]) @ W_et + bias ----------
// Block = 64 dsts, 4 waves (wave w: rows (w&1)*32, cols (w>>1)*64).
// Per et: 4 threads/dst gather+sum the segment's feats rows (f32), scale by inv,
// pack bf16 into the swizzled A-tile, then 32 MFMA/wave accumulate into C.
// Inv folded into A => C accumulates across ets. Epilogue: bias of present ets.
__global__ __launch_bounds__(256, 3) void fused_k(
    const unsigned short* __restrict__ featsbf,
    const unsigned short* __restrict__ WeT,
    const float* __restrict__ b_edge,
    const int* __restrict__ poff, const int* __restrict__ esrc,
    float* __restrict__ agg, int N) {
  __shared__ unsigned char Asm[DSTB * 264];     // A tile bf16, xor-swizzled (16.9 KB)
  __shared__ int spoff[DSTB * TRELS + 1];       // block's pair offsets (4.1 KB)
  __shared__ unsigned short smask[DSTB];        // present-et mask per dst
  int tid = threadIdx.x;
  int tile = blockIdx.x;
  int lane = tid & 63, w = tid >> 6;
  int m = lane & 15, qd = lane >> 4;
  int rw = (w & 1) * 32, cw = (w >> 1) * 64;

  int M = N * TRELS;
  // stage poff slice (1025 ints)
  for (int i = tid; i < DSTB * TRELS + 1; i += 256) {
    int g = tile * (DSTB * TRELS) + i;
    spoff[i] = (g <= M) ? poff[g] : poff[M];
  }
  __syncthreads();

  int r = tid >> 2, cg = tid & 3;     // dst-local row, col-group (32 cols each)
  unsigned mask = 0;

  f32x4 acc[2][4];
#pragma unroll
  for (int i = 0; i < 2; ++i)
#pragma unroll
    for (int j = 0; j < 4; ++j) acc[i][j] = (f32x4){0.f, 0.f, 0.f, 0.f};

  for (int et = 0; et < TRELS; ++et) {
    // ---- A build: sum feats rows of segment (d, et), cols [cg*32, cg*32+32) ----
    int s0 = spoff[r * TRELS + et];
    int s1 = spoff[r * TRELS + et + 1];
    float fa[32];
#pragma unroll
    for (int z = 0; z < 32; ++z) fa[z] = 0.f;
    for (int e = s0; e < s1; ++e) {
      int sn = esrc[e];
      const u32x4* fp = reinterpret_cast<const u32x4*>(featsbf + (size_t)sn * D + cg * 32);
      u32x4 vv[4];
#pragma unroll
      for (int t = 0; t < 4; ++t) vv[t] = fp[t];
#pragma unroll
      for (int t = 0; t < 4; ++t)
#pragma unroll
        for (int z = 0; z < 4; ++z) {
          float lo, hi;
          bfpair(vv[t][z], lo, hi);
          fa[t * 8 + z * 2] += lo; fa[t * 8 + z * 2 + 1] += hi;
        }
    }
    int c = s1 - s0;
    float inv = (c > 0) ? 1.0f / (float)c : 0.0f;
    if (c > 0) mask |= (1u << et);
    // pack scaled bf16 into swizzled A tile (always write: clears stale rows)
#pragma unroll
    for (int cc = 0; cc < 4; ++cc) {
      u32x4 pk;
#pragma unroll
      for (int z = 0; z < 4; ++z) {
        unsigned l0 = f2bf(fa[cc * 8 + z * 2] * inv);
        unsigned h0 = f2bf(fa[cc * 8 + z * 2 + 1] * inv);
        pk[z] = l0 | (h0 << 16);
      }
      int cu = cg * 4 + cc;   // 16B-column unit 0..15
      *reinterpret_cast<u32x4*>(&Asm[r * 256 + ((cu ^ (r & 7)) << 4)]) = pk;
    }
    // ---- B frags (loaded after fa dies -> lower VGPR peak) ----
    const unsigned short* WB = WeT + (size_t)et * (D * D);
    bf16x8 bfr[4][4];
#pragma unroll
    for (int ks = 0; ks < 4; ++ks)
#pragma unroll
      for (int j = 0; j < 4; ++j)
        bfr[ks][j] = *reinterpret_cast<const bf16x8*>(WB + (cw + j * 16 + m) * D + ks * 32 + qd * 8);
    __syncthreads();
    // ---- MFMA: 2 i-tiles x 4 j-tiles x 4 k-steps ----
#pragma unroll
    for (int ks = 0; ks < 4; ++ks) {
      bf16x8 a[2];
#pragma unroll
      for (int i = 0; i < 2; ++i) {
        int rr = rw + i * 16 + m;
        int cu = ks * 4 + qd;
        a[i] = *reinterpret_cast<const bf16x8*>(&Asm[rr * 256 + ((cu ^ (rr & 7)) << 4)]);
      }
#pragma unroll
      for (int i = 0; i < 2; ++i)
#pragma unroll
        for (int j = 0; j < 4; ++j)
          acc[i][j] = __builtin_amdgcn_mfma_f32_16x16x32_bf16(a[i], bfr[ks][j], acc[i][j], 0, 0, 0);
    }
    __syncthreads();
  }

  if (cg == 0) smask[r] = (unsigned short)mask;

  // ---- epilogue: 2 halves of 32 rows via f32 LDS repack (reuse Asm: 32x528B) ----
  float* Cf = reinterpret_cast<float*>(Asm);
#pragma unroll
  for (int half = 0; half < 2; ++half) {
    __syncthreads();
    if ((w & 1) == half) {
#pragma unroll
      for (int i = 0; i < 2; ++i)
#pragma unroll
        for (int j = 0; j < 4; ++j)
#pragma unroll
          for (int reg = 0; reg < 4; ++reg) {
            int rl = i * 16 + qd * 4 + reg;   // row within half, 0..31
            Cf[rl * 132 + cw + j * 16 + m] = acc[i][j][reg];
          }
    }
    __syncthreads();
#pragma unroll
    for (int cp = 0; cp < 4; ++cp) {
      int o = cp * 4096 + tid * 16;           // byte offset in 32x512B half tile
      int rl = o >> 9;
      int dd = tile * DSTB + half * 32 + rl;
      if (dd < N) {
        int col = (o & 511) >> 2;
        f32x4 cv = *reinterpret_cast<const f32x4*>((char*)Cf + rl * 528 + (o & 511));
        unsigned mk = smask[half * 32 + rl];
        while (mk) {
          int et = __builtin_ctz(mk); mk &= mk - 1;
          f32x4 b4 = *reinterpret_cast<const f32x4*>(b_edge + et * D + col);
#pragma unroll
          for (int z = 0; z < 4; ++z) cv[z] += b4[z];
        }
        *reinterpret_cast<f32x4*>(agg + (size_t)dd * D + col) = cv;
      }
    }
  }
}

// ---------- node gather-GEMM: out = relu(feats@Wn[tn] + bn[tn] + agg) ----------
// Epilogue: two fp32 half-tile passes through LDS, fused agg+bias+relu on coalesced readout.
__global__ __launch_bounds__(256) void node_gemm_k(
    const unsigned short* __restrict__ featsbf,
    const unsigned short* __restrict__ WnT,
    const float* __restrict__ b_node,
    const int* __restrict__ nsorted, const int* __restrict__ misc,
    const float* __restrict__ agg,
    float* __restrict__ out) {
  __shared__ unsigned char Asm[128 * 264];
  __shared__ int sm_node[128];
  __shared__ int s_ntb[9];
  int tid = threadIdx.x;
  if (tid < 9) s_ntb[tid] = misc[9 + tid];
  __syncthreads();
  int bid = blockIdx.x;
  if (bid >= s_ntb[8]) return;
  int t = 0;
  while (bid >= s_ntb[t + 1]) ++t;
  int tile = bid - s_ntb[t];
  int noff_t = misc[t];
  int cntT = misc[t + 1] - noff_t;

  int lane = tid & 63, w = tid >> 6;
  int m = lane & 15, q = lane >> 4;
  int rw = (w & 1) * 64, cw = (w >> 1) * 64;

  const unsigned short* WB = WnT + t * (D * D);
  bf16x8 bfr[4][4];
#pragma unroll
  for (int ks = 0; ks < 4; ++ks)
#pragma unroll
    for (int j = 0; j < 4; ++j)
      bfr[ks][j] = *reinterpret_cast<const bf16x8*>(WB + (cw + j * 16 + m) * D + ks * 32 + q * 8);

  int r = tid >> 1, h = tid & 1;
  int gidx = tile * 128 + r;
  bool rv = gidx < cntT;
  int node = 0;
  if (rv) node = nsorted[noff_t + gidx];
  if (h == 0) sm_node[r] = rv ? node : -1;
  if (rv) {
    const u32x4* gp = reinterpret_cast<const u32x4*>(featsbf + (size_t)node * D);
#pragma unroll
    for (int cc = 0; cc < 8; ++cc) {
      int c = h * 8 + cc;
      *reinterpret_cast<u32x4*>(&Asm[r * 256 + ((c ^ (r & 7)) << 4)]) = gp[c];
    }
  }
  __syncthreads();

  f32x4 acc[4][4];
#pragma unroll
  for (int i = 0; i < 4; ++i)
#pragma unroll
    for (int j = 0; j < 4; ++j) acc[i][j] = (f32x4){0.f, 0.f, 0.f, 0.f};

#pragma unroll
  for (int ks = 0; ks < 4; ++ks) {
    bf16x8 a[4];
#pragma unroll
    for (int i = 0; i < 4; ++i) {
      int rr = rw + i * 16 + m;
      int c = ks * 4 + q;
      a[i] = *reinterpret_cast<const bf16x8*>(&Asm[rr * 256 + ((c ^ (rr & 7)) << 4)]);
    }
#pragma unroll
    for (int i = 0; i < 4; ++i)
#pragma unroll
      for (int j = 0; j < 4; ++j)
        acc[i][j] = __builtin_amdgcn_mfma_f32_16x16x32_bf16(a[i], bfr[ks][j], acc[i][j], 0, 0, 0);
  }

  // epilogue: two half-tile fp32 passes through LDS (pitch 132 floats = 528 B, 64 rows)
  const float* bnp = b_node + t * D;
  float* Cf = reinterpret_cast<float*>(Asm);
  __syncthreads();
#pragma unroll
  for (int half = 0; half < 2; ++half) {
    if ((w & 1) == half) {
#pragma unroll
      for (int i = 0; i < 4; ++i)
#pragma unroll
        for (int j = 0; j < 4; ++j)
#pragma unroll
          for (int reg = 0; reg < 4; ++reg) {
            int rl = i * 16 + q * 4 + reg;   // local row 0..63
            Cf[rl * 132 + cw + j * 16 + m] = acc[i][j][reg];
          }
    }
    __syncthreads();
#pragma unroll
    for (int cp = 0; cp < 8; ++cp) {
      int o = cp * 4096 + tid * 16;     // byte offset in 64x512B half tile
      int rl = o >> 9;
      int nd = sm_node[half * 64 + rl];
      if (nd >= 0) {
        int col = (o & 511) >> 2;
        f32x4 c = *reinterpret_cast<const f32x4*>((char*)Cf + rl * 528 + (o & 511));
        f32x4 a = *reinterpret_cast<const f32x4*>(agg + (size_t)nd * D + col);
        f32x4 b4 = *reinterpret_cast<const f32x4*>(bnp + col);
        f32x4 res;
#pragma unroll
        for (int z = 0; z < 4; ++z) res[z] = fmaxf(c[z] + a[z] + b4[z], 0.f);
        *reinterpret_cast<f32x4*>(out + (size_t)nd * D + col) = res;
      }
    }
    __syncthreads();
  }
}

static inline size_t align256(size_t x) { return (x + 255) & ~(size_t)255; }

extern "C" void kernel_launch(void* const* d_in, const int* in_sizes, int n_in,
                              void* d_out, int out_size, void* d_ws, size_t ws_size,
                              hipStream_t stream) {
  const float* feats  = (const float*)d_in[0];
  const float* W_edge = (const float*)d_in[1];
  const float* b_edge = (const float*)d_in[2];
  const float* W_node = (const float*)d_in[3];
  const float* b_node = (const float*)d_in[4];
  const int* src    = (const int*)d_in[5];
  const int* dst    = (const int*)d_in[6];
  const int* ntypes = (const int*)d_in[7];
  const int* etypes = (const int*)d_in[8];
  int N = in_sizes[0] / D;   // 50000
  int E = in_sizes[5];       // 640000
  int M = N * TRELS;         // 800000 pair slots

  char* ws = (char*)d_ws;
  size_t o_cnt  = 0;
  size_t o_misc = align256(o_cnt + (size_t)M * 4);
  size_t zend   = align256(o_misc + 512);
  size_t o_poff = zend;
  size_t o_pcur = align256(o_poff + (size_t)(M + 1) * 4);
  size_t o_bsum = align256(o_pcur + (size_t)M * 4);
  size_t o_esrc = align256(o_bsum + 4096);
  size_t o_ns   = align256(o_esrc + (size_t)E * 4);
  size_t o_fb   = align256(o_ns + (size_t)N * 4);
  size_t o_we   = align256(o_fb + (size_t)N * D * 2);
  size_t o_wn   = align256(o_we + (size_t)TRELS * D * D * 2);
  size_t o_agg  = align256(o_wn + (size_t)NTYPES * D * D * 2);

  int* cnt = (int*)(ws + o_cnt);
  int* misc = (int*)(ws + o_misc);
  int* poff = (int*)(ws + o_poff);
  int* pcur = (int*)(ws + o_pcur);
  int* bsum = (int*)(ws + o_bsum);
  int* esrc = (int*)(ws + o_esrc);
  int* nsorted = (int*)(ws + o_ns);
  unsigned short* featsbf = (unsigned short*)(ws + o_fb);
  unsigned short* WeT = (unsigned short*)(ws + o_we);
  unsigned short* WnT = (unsigned short*)(ws + o_wn);
  float* agg = (float*)(ws + o_agg);

  (void)hipMemsetAsync(ws, 0, zend, stream);

  int nfeat = N * D;
  int ptot = nfeat + TRELS * D * D + NTYPES * D * D;
  prep_k<<<(ptot + 255) / 256, 256, 0, stream>>>(feats, W_edge, W_node, featsbf, WeT, WnT, nfeat);

  int hgrid = ((E > N ? E : N) + 255) / 256;
  hist_k<<<hgrid, 256, 0, stream>>>(dst, etypes, ntypes, E, N, cnt, misc + 26);

  int nb = (M + 1023) / 1024;   // 782
  scan1_k<<<nb, 256, 0, stream>>>(cnt, poff, bsum, M);
  scan2_k<<<1, 64, 0, stream>>>(misc, bsum, nb);
  scan3_k<<<nb, 256, 0, stream>>>(poff, pcur, bsum, M, E);

  scatter_k<<<hgrid, 256, 0, stream>>>(src, dst, etypes, ntypes, E, N, misc, pcur, esrc, nsorted);

  int fgrid = (N + DSTB - 1) / DSTB;   // 782
  fused_k<<<fgrid, 256, 0, stream>>>(featsbf, WeT, b_edge, poff, esrc, agg, N);

  int mtiles = (N + 127) / 128;
  int ngrid = mtiles + NTYPES;
  node_gemm_k<<<ngrid, 256, 0, stream>>>(featsbf, WnT, b_node, nsorted, misc, agg, (float*)d_out);
}

// Round 6
// 359.799 us; speedup vs baseline: 1.2839x; 1.2839x over previous
//
#include <hip/hip_runtime.h>
#include <hip/hip_bf16.h>
#include <stdint.h>

// ERGCNConv on MI355X (gfx950).
// R8: revert to R4 skeleton (best verified). Changes vs R4:
//   - agg_k: 2 dsts per wave (2x independent gather streams; latency-bound fix)
//   - prep+hist fused (block-split); W transpose via LDS tile (coalesced reads)
//   - hw_gemm: R4 form + XCD swizzle, plain stores (no NT)
// Pipeline: memset | prep_hist | scan1/2/3 | scatter | hw_gemm | agg | node_gemm

#define D 128
#define TRELS 16
#define NTYPES 8

typedef __bf16 bf16x8 __attribute__((ext_vector_type(8)));
typedef float f32x4 __attribute__((ext_vector_type(4)));
typedef unsigned int u32x4 __attribute__((ext_vector_type(4)));

__device__ __forceinline__ unsigned short f2bf(float f) {
  union { float f; unsigned u; } v; v.f = f;
  unsigned u = v.u;
  return (unsigned short)((u + 0x7FFFu + ((u >> 16) & 1u)) >> 16);  // RNE
}
// unpack 2 bf16 from a dword: lo = bits<<16, hi = bits&0xffff0000
__device__ __forceinline__ void bfpair(unsigned u, float& lo, float& hi) {
  union { unsigned u; float f; } a, b;
  a.u = u << 16; b.u = u & 0xffff0000u;
  lo = a.f; hi = b.f;
}

// ---------- fused prep + hist ----------
// blocks [0, fb): feats f32 -> bf16 (8 elems/thread, vectorized)
// blocks [fb, fb+wb): W_edge/W_node transpose to [t][n][k] bf16 via 64x64 LDS tile
// blocks [fb+wb, ...): hist: cnt[dst*16+et]++, node-type histogram
__global__ void prep_hist_k(const float* __restrict__ feats,
                            const float* __restrict__ We,
                            const float* __restrict__ Wn,
                            const int* __restrict__ dst, const int* __restrict__ etypes,
                            const int* __restrict__ ntypes,
                            unsigned short* __restrict__ featsbf,
                            unsigned short* __restrict__ WeT,
                            unsigned short* __restrict__ WnT,
                            int* __restrict__ cnt, int* __restrict__ nhist,
                            int N, int E, int nfeat, int fb, int wb) {
  __shared__ unsigned short Ts[64][65];
  __shared__ int sh_n[NTYPES];
  int b = blockIdx.x;
  int tid = threadIdx.x;
  if (b < fb) {
    int i = (b * 256 + tid) * 8;
    if (i + 8 <= nfeat) {
      const f32x4* fp = reinterpret_cast<const f32x4*>(feats + i);
      f32x4 a = fp[0], c = fp[1];
      u32x4 pk;
      pk[0] = (unsigned)f2bf(a[0]) | ((unsigned)f2bf(a[1]) << 16);
      pk[1] = (unsigned)f2bf(a[2]) | ((unsigned)f2bf(a[3]) << 16);
      pk[2] = (unsigned)f2bf(c[0]) | ((unsigned)f2bf(c[1]) << 16);
      pk[3] = (unsigned)f2bf(c[2]) | ((unsigned)f2bf(c[3]) << 16);
      *reinterpret_cast<u32x4*>(featsbf + i) = pk;
    }
    return;
  }
  b -= fb;
  if (b < wb) {
    int mat = b >> 2, tq = b & 3;
    const float* Ws = (mat < TRELS) ? (We + (size_t)mat * D * D)
                                    : (Wn + (size_t)(mat - TRELS) * D * D);
    unsigned short* Wd = (mat < TRELS) ? (WeT + (size_t)mat * D * D)
                                       : (WnT + (size_t)(mat - TRELS) * D * D);
    int k0 = (tq >> 1) * 64, n0 = (tq & 1) * 64;
#pragma unroll
    for (int p = 0; p < 16; ++p) {
      int kr = (tid >> 6) + p * 4, cn = tid & 63;
      Ts[kr][cn] = f2bf(Ws[(k0 + kr) * D + n0 + cn]);   // coalesced read
    }
    __syncthreads();
#pragma unroll
    for (int p = 0; p < 16; ++p) {
      int nr = (tid >> 6) + p * 4, ck = tid & 63;
      Wd[(n0 + nr) * D + k0 + ck] = Ts[ck][nr];          // coalesced write
    }
    return;
  }
  b -= wb;
  if (tid < NTYPES) sh_n[tid] = 0;
  __syncthreads();
  int g = b * 256 + tid;
  if (g < E) atomicAdd(&cnt[dst[g] * TRELS + etypes[g]], 1);
  if (g < N) atomicAdd(&sh_n[ntypes[g]], 1);
  __syncthreads();
  if (tid < NTYPES && sh_n[tid]) atomicAdd(&nhist[tid], sh_n[tid]);
}

// misc layout (ints): noff[0..8], ntb[9..17], ncur[18..25], nhist[26..33], bsum[64..127]
// ---------- scan1: deg from cnt rows; block-local exclusive scan -> doff; block sums ----------
__global__ void scan1_k(const int* __restrict__ cnt, int* __restrict__ doff,
                        int* __restrict__ bsum, int N) {
  __shared__ int sd[256];
  int b = blockIdx.x, tid = threadIdx.x;
  int base = b * 1024 + tid * 4;
  int v[4]; int tot = 0;
  for (int j = 0; j < 4; ++j) {
    int i = base + j;
    int dg = 0;
    if (i < N) {
      const int* row = cnt + i * TRELS;
#pragma unroll
      for (int et = 0; et < TRELS; ++et) dg += row[et];
    }
    v[j] = tot; tot += dg;
  }
  sd[tid] = tot;
  __syncthreads();
  for (int off = 1; off < 256; off <<= 1) {
    int t = (tid >= off) ? sd[tid - off] : 0;
    __syncthreads();
    sd[tid] += t;
    __syncthreads();
  }
  int excl = sd[tid] - tot;
  for (int j = 0; j < 4; ++j) {
    int i = base + j;
    if (i < N) doff[i] = excl + v[j];
  }
  if (tid == 255) bsum[b] = sd[255];
}

// ---------- scan2: scan block sums; node-type scan ----------
__global__ void scan2_k(int* __restrict__ misc, int* __restrict__ bsum, int nb) {
  if (threadIdx.x != 0) return;
  int run = 0;
  for (int b = 0; b < nb; ++b) { int t = bsum[b]; bsum[b] = run; run += t; }
  int* noff = misc; int* ntb = misc + 9; int* ncur = misc + 18; int* nhist = misc + 26;
  int s = 0, ts = 0;
  for (int t = 0; t < NTYPES; ++t) {
    noff[t] = s; ncur[t] = s; ntb[t] = ts;
    s += nhist[t]; ts += (nhist[t] + 127) >> 7;
  }
  noff[NTYPES] = s; ntb[NTYPES] = ts;
}

// ---------- scan3: add block offsets; init dcur; doff[N] = E ----------
__global__ void scan3_k(int* __restrict__ doff, int* __restrict__ dcur,
                        const int* __restrict__ bsum, int N, int E) {
  int b = blockIdx.x, tid = threadIdx.x;
  int add = bsum[b];
  int base = b * 1024 + tid * 4;
  for (int j = 0; j < 4; ++j) {
    int i = base + j;
    if (i < N) { int o = doff[i] + add; doff[i] = o; dcur[i] = o; }
  }
  if (b == 0 && tid == 0) doff[N] = E;
}

// ---------- scatter: edges -> dst-sorted packed keys; nodes -> ntype-sorted ----------
__global__ void scatter_k(const int* __restrict__ src, const int* __restrict__ dst,
                          const int* __restrict__ etypes, const int* __restrict__ ntypes,
                          int E, int N, int* __restrict__ misc,
                          int* __restrict__ dcur,
                          int* __restrict__ edst, int* __restrict__ nsorted) {
  __shared__ int lc_n[NTYPES], lb_n[NTYPES];
  int tid = threadIdx.x;
  if (tid < NTYPES) lc_n[tid] = 0;
  __syncthreads();
  int g = blockIdx.x * 256 + tid;
  if (g < E) {
    int d = dst[g];
    int pos = atomicAdd(&dcur[d], 1);
    edst[pos] = src[g] * TRELS + etypes[g];   // packed key
  }
  int tn = -1, idn = 0;
  if (g < N) { tn = ntypes[g]; idn = atomicAdd(&lc_n[tn], 1); }
  __syncthreads();
  if (tid < NTYPES && lc_n[tid]) lb_n[tid] = atomicAdd(&misc[18 + tid], lc_n[tid]);
  __syncthreads();
  if (g < N) nsorted[lb_n[tn] + idn] = g;
}

// ---------- hW GEMM: hW[et] = feats @ W_et (bf16 out), dense, no gather ----------
// R4 structure: block = (tile, et), 4 waves, A in swizzled LDS, B in regs,
// bf16 LDS repack epilogue. Bijective XCD-chunk swizzle (et fastest) keeps each
// feats tile on one XCD's L2 (FETCH 102->8.5 MB, verified R4).
__global__ __launch_bounds__(256) void hw_gemm_k(
    const unsigned short* __restrict__ featsbf,
    const unsigned short* __restrict__ WeT,
    unsigned short* __restrict__ hW, int N, int mtiles) {
  __shared__ unsigned char Asm[128 * 264];
  int tid = threadIdx.x;

  int G = mtiles * 16;
  int q = G >> 3, rmod = G & 7;
  int xcd = blockIdx.x & 7, bidx = blockIdx.x >> 3;
  int wrk = (xcd < rmod) ? (xcd * (q + 1) + bidx)
                         : (rmod * (q + 1) + (xcd - rmod) * q + bidx);
  int tile = wrk >> 4;
  int et = wrk & 15;

  int lane = tid & 63, w = tid >> 6;
  int m = lane & 15, qd = lane >> 4;
  int rw = (w & 1) * 64, cw = (w >> 1) * 64;

  const unsigned short* WB = WeT + (size_t)et * (D * D);
  bf16x8 bfr[4][4];
#pragma unroll
  for (int ks = 0; ks < 4; ++ks)
#pragma unroll
    for (int j = 0; j < 4; ++j)
      bfr[ks][j] = *reinterpret_cast<const bf16x8*>(WB + (cw + j * 16 + m) * D + ks * 32 + qd * 8);

  int r = tid >> 1, h = tid & 1;
  int row = tile * 128 + r;
  if (row < N) {
    const u32x4* gp = reinterpret_cast<const u32x4*>(featsbf + (size_t)row * D);
#pragma unroll
    for (int cc = 0; cc < 8; ++cc) {
      int c = h * 8 + cc;
      *reinterpret_cast<u32x4*>(&Asm[r * 256 + ((c ^ (r & 7)) << 4)]) = gp[c];
    }
  }
  __syncthreads();

  f32x4 acc[4][4];
#pragma unroll
  for (int i = 0; i < 4; ++i)
#pragma unroll
    for (int j = 0; j < 4; ++j) acc[i][j] = (f32x4){0.f, 0.f, 0.f, 0.f};

#pragma unroll
  for (int ks = 0; ks < 4; ++ks) {
    bf16x8 a[4];
#pragma unroll
    for (int i = 0; i < 4; ++i) {
      int rr = rw + i * 16 + m;
      int c = ks * 4 + qd;
      a[i] = *reinterpret_cast<const bf16x8*>(&Asm[rr * 256 + ((c ^ (rr & 7)) << 4)]);
    }
#pragma unroll
    for (int i = 0; i < 4; ++i)
#pragma unroll
      for (int j = 0; j < 4; ++j)
        acc[i][j] = __builtin_amdgcn_mfma_f32_16x16x32_bf16(a[i], bfr[ks][j], acc[i][j], 0, 0, 0);
  }

  __syncthreads();
  unsigned short* Cs = reinterpret_cast<unsigned short*>(Asm);
#pragma unroll
  for (int i = 0; i < 4; ++i)
#pragma unroll
    for (int j = 0; j < 4; ++j)
#pragma unroll
      for (int reg = 0; reg < 4; ++reg) {
        int rr = rw + i * 16 + qd * 4 + reg;  // C/D: row = quad*4+reg, col = m
        Cs[rr * 132 + cw + j * 16 + m] = f2bf(acc[i][j][reg]);
      }
  __syncthreads();
  char* gout = (char*)(hW + ((size_t)et * N + (size_t)tile * 128) * D);
#pragma unroll
  for (int cp = 0; cp < 8; ++cp) {
    int o = cp * 4096 + tid * 16;     // byte offset in logical 128x256B tile
    int rloc = o >> 8;
    if (tile * 128 + rloc < N) {
      u32x4 v = *reinterpret_cast<const u32x4*>(&Asm[rloc * 264 + (o & 255)]);
      *reinterpret_cast<u32x4*>(gout + o) = v;
    }
  }
}

// ---------- agg: 2 dsts per wave, 16B/lane gathers, xor-16/32 combine ----------
// Lanes 0..15 hold inv for d0, 16..31 for d1. Lane group g handles row j+g of each
// 4-row batch for BOTH dsts (2 independent gather streams). Write: g<2 -> d0, g>=2 -> d1.
__global__ __launch_bounds__(256) void agg_k(
    const unsigned short* __restrict__ hW,
    const float* __restrict__ b_edge,
    const int* __restrict__ cnt,
    const int* __restrict__ doff, const int* __restrict__ edst,
    float* __restrict__ agg, int N) {
  int tid = threadIdx.x;
  int lane = tid & 63, w = tid >> 6;
  int d0 = blockIdx.x * 8 + w * 2;
  if (d0 >= N) return;
  int d1 = d0 + 1;
  bool has1 = d1 < N;

  int cv = 0;
  if (lane < 32) {
    int dd = d0 + (lane >> 4);
    if (dd < N) cv = cnt[dd * TRELS + (lane & 15)];
  }
  float invl = (cv > 0) ? 1.0f / (float)cv : 0.0f;

  int g = lane >> 4, sub = lane & 15;

  int s0 = doff[d0];
  int e0 = doff[d0 + 1];
  int e1 = has1 ? doff[d0 + 2] : e0;
  int n0 = e0 - s0, n1 = e1 - e0;   // d1's range starts at e0 (contiguous CSR)
  int nmax = (n0 > n1) ? n0 : n1;

  float acc0[8], acc1[8];
#pragma unroll
  for (int z = 0; z < 8; ++z) { acc0[z] = 0.f; acc1[z] = 0.f; }

  for (int base = 0; base < nmax; base += 64) {
    int key0 = 0, key1 = 0;
    if (base + lane < n0) key0 = edst[s0 + base + lane];
    if (base + lane < n1) key1 = edst[e0 + base + lane];
    int c0 = n0 - base; c0 = (c0 > 64) ? 64 : ((c0 < 0) ? 0 : c0);
    int c1 = n1 - base; c1 = (c1 > 64) ? 64 : ((c1 < 0) ? 0 : c1);
    int cm = (c0 > c1) ? c0 : c1;
#pragma unroll 2
    for (int j = 0; j < cm; j += 4) {
      int rr = j + g;
      int k0 = __shfl(key0, rr, 64);
      int k1 = __shfl(key1, rr, 64);
      float iv0 = __shfl(invl, k0 & 15, 64);
      float iv1 = __shfl(invl, 16 + (k1 & 15), 64);
      if (rr < c0) {
        const unsigned short* hp =
            hW + ((size_t)(k0 & 15) * N + (size_t)(k0 >> 4)) * D + sub * 8;
        u32x4 hv = *reinterpret_cast<const u32x4*>(hp);
        float lo, hi;
        bfpair(hv.x, lo, hi); acc0[0] += iv0 * lo; acc0[1] += iv0 * hi;
        bfpair(hv.y, lo, hi); acc0[2] += iv0 * lo; acc0[3] += iv0 * hi;
        bfpair(hv.z, lo, hi); acc0[4] += iv0 * lo; acc0[5] += iv0 * hi;
        bfpair(hv.w, lo, hi); acc0[6] += iv0 * lo; acc0[7] += iv0 * hi;
      }
      if (rr < c1) {
        const unsigned short* hp =
            hW + ((size_t)(k1 & 15) * N + (size_t)(k1 >> 4)) * D + sub * 8;
        u32x4 hv = *reinterpret_cast<const u32x4*>(hp);
        float lo, hi;
        bfpair(hv.x, lo, hi); acc1[0] += iv1 * lo; acc1[1] += iv1 * hi;
        bfpair(hv.y, lo, hi); acc1[2] += iv1 * lo; acc1[3] += iv1 * hi;
        bfpair(hv.z, lo, hi); acc1[4] += iv1 * lo; acc1[5] += iv1 * hi;
        bfpair(hv.w, lo, hi); acc1[6] += iv1 * lo; acc1[7] += iv1 * hi;
      }
    }
  }

  // combine the 4 group-partials (columns align across groups)
#pragma unroll
  for (int z = 0; z < 8; ++z) {
    acc0[z] += __shfl_xor(acc0[z], 16, 64);
    acc0[z] += __shfl_xor(acc0[z], 32, 64);
    acc1[z] += __shfl_xor(acc1[z], 16, 64);
    acc1[z] += __shfl_xor(acc1[z], 32, 64);
  }

  // lane's target: g<2 -> d0 cols, g>=2 -> d1 cols
  int cb = sub * 8 + (g & 1) * 4;
  bool lo2 = (g < 2);
  f32x4 res;
#pragma unroll
  for (int z = 0; z < 4; ++z) res[z] = lo2 ? acc0[(g & 1) * 4 + z] : acc1[(g & 1) * 4 + z];
  int srcl = lo2 ? 0 : 16;
#pragma unroll
  for (int et = 0; et < TRELS; ++et) {
    int cc = __shfl(cv, srcl + et, 64);
    if (cc > 0) {
      f32x4 b4 = *reinterpret_cast<const f32x4*>(b_edge + et * D + cb);
#pragma unroll
      for (int z = 0; z < 4; ++z) res[z] += b4[z];
    }
  }
  int dT = lo2 ? d0 : d1;
  if (lo2 || has1)
    *reinterpret_cast<f32x4*>(agg + (size_t)dT * D + cb) = res;
}

// ---------- node gather-GEMM: out = relu(feats@Wn[tn] + bn[tn] + agg) ----------
__global__ __launch_bounds__(256) void node_gemm_k(
    const unsigned short* __restrict__ featsbf,
    const unsigned short* __restrict__ WnT,
    const float* __restrict__ b_node,
    const int* __restrict__ nsorted, const int* __restrict__ misc,
    const float* __restrict__ agg,
    float* __restrict__ out) {
  __shared__ unsigned char Asm[128 * 264];
  __shared__ int sm_node[128];
  __shared__ int s_ntb[9];
  int tid = threadIdx.x;
  if (tid < 9) s_ntb[tid] = misc[9 + tid];
  __syncthreads();
  int bid = blockIdx.x;
  if (bid >= s_ntb[8]) return;
  int t = 0;
  while (bid >= s_ntb[t + 1]) ++t;
  int tile = bid - s_ntb[t];
  int noff_t = misc[t];
  int cntT = misc[t + 1] - noff_t;

  int lane = tid & 63, w = tid >> 6;
  int m = lane & 15, q = lane >> 4;
  int rw = (w & 1) * 64, cw = (w >> 1) * 64;

  const unsigned short* WB = WnT + t * (D * D);
  bf16x8 bfr[4][4];
#pragma unroll
  for (int ks = 0; ks < 4; ++ks)
#pragma unroll
    for (int j = 0; j < 4; ++j)
      bfr[ks][j] = *reinterpret_cast<const bf16x8*>(WB + (cw + j * 16 + m) * D + ks * 32 + q * 8);

  int r = tid >> 1, h = tid & 1;
  int gidx = tile * 128 + r;
  bool rv = gidx < cntT;
  int node = 0;
  if (rv) node = nsorted[noff_t + gidx];
  if (h == 0) sm_node[r] = rv ? node : -1;
  if (rv) {
    const u32x4* gp = reinterpret_cast<const u32x4*>(featsbf + (size_t)node * D);
#pragma unroll
    for (int cc = 0; cc < 8; ++cc) {
      int c = h * 8 + cc;
      *reinterpret_cast<u32x4*>(&Asm[r * 256 + ((c ^ (r & 7)) << 4)]) = gp[c];
    }
  }
  __syncthreads();

  f32x4 acc[4][4];
#pragma unroll
  for (int i = 0; i < 4; ++i)
#pragma unroll
    for (int j = 0; j < 4; ++j) acc[i][j] = (f32x4){0.f, 0.f, 0.f, 0.f};

#pragma unroll
  for (int ks = 0; ks < 4; ++ks) {
    bf16x8 a[4];
#pragma unroll
    for (int i = 0; i < 4; ++i) {
      int rr = rw + i * 16 + m;
      int c = ks * 4 + q;
      a[i] = *reinterpret_cast<const bf16x8*>(&Asm[rr * 256 + ((c ^ (rr & 7)) << 4)]);
    }
#pragma unroll
    for (int i = 0; i < 4; ++i)
#pragma unroll
      for (int j = 0; j < 4; ++j)
        acc[i][j] = __builtin_amdgcn_mfma_f32_16x16x32_bf16(a[i], bfr[ks][j], acc[i][j], 0, 0, 0);
  }

  const float* bnp = b_node + t * D;
  float* Cf = reinterpret_cast<float*>(Asm);
  __syncthreads();
#pragma unroll
  for (int half = 0; half < 2; ++half) {
    if ((w & 1) == half) {
#pragma unroll
      for (int i = 0; i < 4; ++i)
#pragma unroll
        for (int j = 0; j < 4; ++j)
#pragma unroll
          for (int reg = 0; reg < 4; ++reg) {
            int rl = i * 16 + q * 4 + reg;   // local row 0..63
            Cf[rl * 132 + cw + j * 16 + m] = acc[i][j][reg];
          }
    }
    __syncthreads();
#pragma unroll
    for (int cp = 0; cp < 8; ++cp) {
      int o = cp * 4096 + tid * 16;     // byte offset in 64x512B half tile
      int rl = o >> 9;
      int nd = sm_node[half * 64 + rl];
      if (nd >= 0) {
        int col = (o & 511) >> 2;
        f32x4 c = *reinterpret_cast<const f32x4*>((char*)Cf + rl * 528 + (o & 511));
        f32x4 a = *reinterpret_cast<const f32x4*>(agg + (size_t)nd * D + col);
        f32x4 b4 = *reinterpret_cast<const f32x4*>(bnp + col);
        f32x4 res;
#pragma unroll
        for (int z = 0; z < 4; ++z) res[z] = fmaxf(c[z] + a[z] + b4[z], 0.f);
        *reinterpret_cast<f32x4*>(out + (size_t)nd * D + col) = res;
      }
    }
    __syncthreads();
  }
}

static inline size_t align256(size_t x) { return (x + 255) & ~(size_t)255; }

extern "C" void kernel_launch(void* const* d_in, const int* in_sizes, int n_in,
                              void* d_out, int out_size, void* d_ws, size_t ws_size,
                              hipStream_t stream) {
  const float* feats  = (const float*)d_in[0];
  const float* W_edge = (const float*)d_in[1];
  const float* b_edge = (const float*)d_in[2];
  const float* W_node = (const float*)d_in[3];
  const float* b_node = (const float*)d_in[4];
  const int* src    = (const int*)d_in[5];
  const int* dst    = (const int*)d_in[6];
  const int* ntypes = (const int*)d_in[7];
  const int* etypes = (const int*)d_in[8];
  int N = in_sizes[0] / D;   // 50000
  int E = in_sizes[5];       // 640000

  char* ws = (char*)d_ws;
  size_t o_cnt  = 0;
  size_t o_misc = align256(o_cnt + (size_t)N * TRELS * 4);
  size_t zend   = align256(o_misc + 512);
  size_t o_doff = zend;
  size_t o_dcur = align256(o_doff + (size_t)(N + 1) * 4);
  size_t o_edst = align256(o_dcur + (size_t)N * 4);
  size_t o_ns   = align256(o_edst + (size_t)E * 4);
  size_t o_fb   = align256(o_ns + (size_t)N * 4);
  size_t o_we   = align256(o_fb + (size_t)N * D * 2);
  size_t o_wn   = align256(o_we + (size_t)TRELS * D * D * 2);
  size_t o_agg  = align256(o_wn + (size_t)NTYPES * D * D * 2);
  size_t o_hw   = align256(o_agg + (size_t)N * D * 4);

  int* cnt = (int*)(ws + o_cnt);
  int* misc = (int*)(ws + o_misc);
  int* doff = (int*)(ws + o_doff);
  int* dcur = (int*)(ws + o_dcur);
  int* edst = (int*)(ws + o_edst);
  int* nsorted = (int*)(ws + o_ns);
  unsigned short* featsbf = (unsigned short*)(ws + o_fb);
  unsigned short* WeT = (unsigned short*)(ws + o_we);
  unsigned short* WnT = (unsigned short*)(ws + o_wn);
  float* agg = (float*)(ws + o_agg);
  unsigned short* hW = (unsigned short*)(ws + o_hw);
  int* bsum = misc + 64;

  (void)hipMemsetAsync(ws, 0, zend, stream);

  int nfeat = N * D;
  int fb = (nfeat / 8 + 255) / 256;                  // 3125
  int wb = (TRELS + NTYPES) * 4;                     // 96
  int hb = ((E > N ? E : N) + 255) / 256;            // 2500
  prep_hist_k<<<fb + wb + hb, 256, 0, stream>>>(feats, W_edge, W_node,
      dst, etypes, ntypes, featsbf, WeT, WnT, cnt, misc + 26, N, E, nfeat, fb, wb);

  int nb = (N + 1023) / 1024;
  scan1_k<<<nb, 256, 0, stream>>>(cnt, doff, bsum, N);
  scan2_k<<<1, 64, 0, stream>>>(misc, bsum, nb);
  scan3_k<<<nb, 256, 0, stream>>>(doff, dcur, bsum, N, E);

  scatter_k<<<hb, 256, 0, stream>>>(src, dst, etypes, ntypes, E, N, misc, dcur, edst, nsorted);

  int mtiles = (N + 127) / 128;
  hw_gemm_k<<<mtiles * 16, 256, 0, stream>>>(featsbf, WeT, hW, N, mtiles);

  agg_k<<<(N + 7) / 8, 256, 0, stream>>>(hW, b_edge, cnt, doff, edst, agg, N);

  int ngrid = mtiles + NTYPES;
  node_gemm_k<<<ngrid, 256, 0, stream>>>(featsbf, WnT, b_node, nsorted, misc, agg, (float*)d_out);
}

// Round 7
// 349.485 us; speedup vs baseline: 1.3218x; 1.0295x over previous
//
#include <hip/hip_runtime.h>
#include <hip/hip_bf16.h>
#include <stdint.h>

// ERGCNConv on MI355X (gfx950).
// R9: R0 baseline kernels restored verbatim (agg/prep/hist/scatter/node_gemm —
//     the R4/R8 agg reworks regressed the "rest" 253.8->270.8 µs; R0's agg wins).
//     Kept: hw_gemm XCD-chunk swizzle (isolated win, FETCH 102->8.5 MB).
//     NEW: used-row predicate stores in hw_gemm — hist builds a per-src used-et
//     bitmap (atomicOr); hw_gemm skips storing hW rows no edge ever reads
//     (~45% of 200 MB write stream eliminated; compute unchanged).
// Pipeline: memset | prep | hist(+bitmap) | scan1/2/3 | scatter
//           | hw_gemm (predicated stores) | agg (R0 form) | node_gemm

#define D 128
#define TRELS 16
#define NTYPES 8

typedef __bf16 bf16x8 __attribute__((ext_vector_type(8)));
typedef float f32x4 __attribute__((ext_vector_type(4)));
typedef unsigned int u32x4 __attribute__((ext_vector_type(4)));

__device__ __forceinline__ unsigned short f2bf(float f) {
  union { float f; unsigned u; } v; v.f = f;
  unsigned u = v.u;
  return (unsigned short)((u + 0x7FFFu + ((u >> 16) & 1u)) >> 16);  // RNE
}
__device__ __forceinline__ float bf2f(unsigned short h) {
  union { unsigned u; float f; } v; v.u = ((unsigned)h) << 16;
  return v.f;
}

// ---------- prep: feats -> bf16; W_edge/W_node -> transposed bf16 [t][n][k] ----------
__global__ void prep_k(const float* __restrict__ feats,
                       const float* __restrict__ We,
                       const float* __restrict__ Wn,
                       unsigned short* __restrict__ featsbf,
                       unsigned short* __restrict__ WeT,
                       unsigned short* __restrict__ WnT,
                       int nfeat) {
  int idx = blockIdx.x * 256 + threadIdx.x;
  if (idx < nfeat) { featsbf[idx] = f2bf(feats[idx]); return; }
  idx -= nfeat;
  if (idx < TRELS * D * D) {
    int t = idx >> 14, rem = idx & 16383;
    int n = rem >> 7, k = rem & 127;
    WeT[idx] = f2bf(We[t * 16384 + k * 128 + n]);   // B^T layout: [n][k]
    return;
  }
  idx -= TRELS * D * D;
  if (idx < NTYPES * D * D) {
    int t = idx >> 14, rem = idx & 16383;
    int n = rem >> 7, k = rem & 127;
    WnT[idx] = f2bf(Wn[t * 16384 + k * 128 + n]);
  }
}

// ---------- hist: cnt[dst*16+et]++, node-type histogram, used-(src,et) bitmap ----------
__global__ void hist_k(const int* __restrict__ src, const int* __restrict__ dst,
                       const int* __restrict__ etypes,
                       const int* __restrict__ ntypes, int E, int N,
                       int* __restrict__ cnt, int* __restrict__ nhist,
                       int* __restrict__ srcuse) {
  __shared__ int sh_n[NTYPES];
  int tid = threadIdx.x;
  if (tid < NTYPES) sh_n[tid] = 0;
  __syncthreads();
  int g = blockIdx.x * 256 + tid;
  if (g < E) {
    int et = etypes[g];
    atomicAdd(&cnt[dst[g] * TRELS + et], 1);
    atomicOr(&srcuse[src[g]], 1 << et);
  }
  if (g < N) atomicAdd(&sh_n[ntypes[g]], 1);
  __syncthreads();
  if (tid < NTYPES && sh_n[tid]) atomicAdd(&nhist[tid], sh_n[tid]);
}

// misc layout (ints): noff[0..8], ntb[9..17], ncur[18..25], nhist[26..33], bsum[64..127]
// ---------- scan1: deg from cnt rows; block-local exclusive scan -> doff; block sums ----------
__global__ void scan1_k(const int* __restrict__ cnt, int* __restrict__ doff,
                        int* __restrict__ bsum, int N) {
  __shared__ int sd[256];
  int b = blockIdx.x, tid = threadIdx.x;
  int base = b * 1024 + tid * 4;
  int v[4]; int tot = 0;
  for (int j = 0; j < 4; ++j) {
    int i = base + j;
    int dg = 0;
    if (i < N) {
      const int* row = cnt + i * TRELS;
#pragma unroll
      for (int et = 0; et < TRELS; ++et) dg += row[et];
    }
    v[j] = tot; tot += dg;
  }
  sd[tid] = tot;
  __syncthreads();
  for (int off = 1; off < 256; off <<= 1) {
    int t = (tid >= off) ? sd[tid - off] : 0;
    __syncthreads();
    sd[tid] += t;
    __syncthreads();
  }
  int excl = sd[tid] - tot;
  for (int j = 0; j < 4; ++j) {
    int i = base + j;
    if (i < N) doff[i] = excl + v[j];
  }
  if (tid == 255) bsum[b] = sd[255];
}

// ---------- scan2: scan block sums; node-type scan ----------
__global__ void scan2_k(int* __restrict__ misc, int* __restrict__ bsum, int nb) {
  if (threadIdx.x != 0) return;
  int run = 0;
  for (int b = 0; b < nb; ++b) { int t = bsum[b]; bsum[b] = run; run += t; }
  int* noff = misc; int* ntb = misc + 9; int* ncur = misc + 18; int* nhist = misc + 26;
  int s = 0, ts = 0;
  for (int t = 0; t < NTYPES; ++t) {
    noff[t] = s; ncur[t] = s; ntb[t] = ts;
    s += nhist[t]; ts += (nhist[t] + 127) >> 7;
  }
  noff[NTYPES] = s; ntb[NTYPES] = ts;
}

// ---------- scan3: add block offsets; init dcur; doff[N] = E ----------
__global__ void scan3_k(int* __restrict__ doff, int* __restrict__ dcur,
                        const int* __restrict__ bsum, int N, int E) {
  int b = blockIdx.x, tid = threadIdx.x;
  int add = bsum[b];
  int base = b * 1024 + tid * 4;
  for (int j = 0; j < 4; ++j) {
    int i = base + j;
    if (i < N) { int o = doff[i] + add; doff[i] = o; dcur[i] = o; }
  }
  if (b == 0 && tid == 0) doff[N] = E;
}

// ---------- scatter: edges -> dst-sorted packed keys; nodes -> ntype-sorted ----------
__global__ void scatter_k(const int* __restrict__ src, const int* __restrict__ dst,
                          const int* __restrict__ etypes, const int* __restrict__ ntypes,
                          int E, int N, int* __restrict__ misc,
                          int* __restrict__ dcur,
                          int* __restrict__ edst, int* __restrict__ nsorted) {
  __shared__ int lc_n[NTYPES], lb_n[NTYPES];
  int tid = threadIdx.x;
  if (tid < NTYPES) lc_n[tid] = 0;
  __syncthreads();
  int g = blockIdx.x * 256 + tid;
  if (g < E) {
    int d = dst[g];
    int pos = atomicAdd(&dcur[d], 1);
    edst[pos] = src[g] * TRELS + etypes[g];   // packed key
  }
  int tn = -1, idn = 0;
  if (g < N) { tn = ntypes[g]; idn = atomicAdd(&lc_n[tn], 1); }
  __syncthreads();
  if (tid < NTYPES && lc_n[tid]) lb_n[tid] = atomicAdd(&misc[18 + tid], lc_n[tid]);
  __syncthreads();
  if (g < N) nsorted[lb_n[tn] + idn] = g;
}

// ---------- hW GEMM: hW[et] = feats @ W_et (bf16 out), dense, no gather ----------
// Block = (tile, et) via bijective XCD-chunk swizzle (et fastest within a tile ->
// each feats tile served by one XCD's L2; FETCH 102->8.5 MB, verified R4).
// NEW: per-row used predicate from srcuse bitmap — skip storing rows no edge reads.
__global__ __launch_bounds__(256) void hw_gemm_k(
    const unsigned short* __restrict__ featsbf,
    const unsigned short* __restrict__ WeT,
    const int* __restrict__ srcuse,
    unsigned short* __restrict__ hW, int N, int mtiles) {
  __shared__ unsigned char Asm[128 * 264];
  __shared__ unsigned char sm_use[128];
  int tid = threadIdx.x;

  int G = mtiles * 16;
  int q = G >> 3, rmod = G & 7;
  int xcd = blockIdx.x & 7, bidx = blockIdx.x >> 3;
  int wrk = (xcd < rmod) ? (xcd * (q + 1) + bidx)
                         : (rmod * (q + 1) + (xcd - rmod) * q + bidx);
  int tile = wrk >> 4;
  int et = wrk & 15;

  int lane = tid & 63, w = tid >> 6;
  int m = lane & 15, qd = lane >> 4;
  int rw = (w & 1) * 64, cw = (w >> 1) * 64;

  const unsigned short* WB = WeT + (size_t)et * (D * D);
  bf16x8 bfr[4][4];
#pragma unroll
  for (int ks = 0; ks < 4; ++ks)
#pragma unroll
    for (int j = 0; j < 4; ++j)
      bfr[ks][j] = *reinterpret_cast<const bf16x8*>(WB + (cw + j * 16 + m) * D + ks * 32 + qd * 8);

  if (tid < 128) {
    int rowu = tile * 128 + tid;
    sm_use[tid] = (rowu < N) ? (unsigned char)((srcuse[rowu] >> et) & 1) : 0;
  }

  int r = tid >> 1, h = tid & 1;
  int row = tile * 128 + r;
  if (row < N) {
    const u32x4* gp = reinterpret_cast<const u32x4*>(featsbf + (size_t)row * D);
#pragma unroll
    for (int cc = 0; cc < 8; ++cc) {
      int c = h * 8 + cc;
      *reinterpret_cast<u32x4*>(&Asm[r * 256 + ((c ^ (r & 7)) << 4)]) = gp[c];
    }
  }
  __syncthreads();

  f32x4 acc[4][4];
#pragma unroll
  for (int i = 0; i < 4; ++i)
#pragma unroll
    for (int j = 0; j < 4; ++j) acc[i][j] = (f32x4){0.f, 0.f, 0.f, 0.f};

#pragma unroll
  for (int ks = 0; ks < 4; ++ks) {
    bf16x8 a[4];
#pragma unroll
    for (int i = 0; i < 4; ++i) {
      int rr = rw + i * 16 + m;
      int c = ks * 4 + qd;
      a[i] = *reinterpret_cast<const bf16x8*>(&Asm[rr * 256 + ((c ^ (rr & 7)) << 4)]);
    }
#pragma unroll
    for (int i = 0; i < 4; ++i)
#pragma unroll
      for (int j = 0; j < 4; ++j)
        acc[i][j] = __builtin_amdgcn_mfma_f32_16x16x32_bf16(a[i], bfr[ks][j], acc[i][j], 0, 0, 0);
  }

  // epilogue: C -> LDS bf16 tile (pitch 132 shorts = 264 B), then coalesced
  // stores of USED rows only.
  __syncthreads();
  unsigned short* Cs = reinterpret_cast<unsigned short*>(Asm);
#pragma unroll
  for (int i = 0; i < 4; ++i)
#pragma unroll
    for (int j = 0; j < 4; ++j)
#pragma unroll
      for (int reg = 0; reg < 4; ++reg) {
        int rr = rw + i * 16 + qd * 4 + reg;  // C/D: row = quad*4+reg, col = m
        Cs[rr * 132 + cw + j * 16 + m] = f2bf(acc[i][j][reg]);
      }
  __syncthreads();
  char* gout = (char*)(hW + ((size_t)et * N + (size_t)tile * 128) * D);
#pragma unroll
  for (int cp = 0; cp < 8; ++cp) {
    int o = cp * 4096 + tid * 16;     // byte offset in logical 128x256B tile
    int rloc = o >> 8;
    if (tile * 128 + rloc < N && sm_use[rloc]) {
      u32x4 v = *reinterpret_cast<const u32x4*>(&Asm[rloc * 264 + (o & 255)]);
      *reinterpret_cast<u32x4*>(gout + o) = v;
    }
  }
}

// ---------- agg: per-dst wave gather-reduce over hW rows (R0 form, verbatim) ----------
__global__ __launch_bounds__(256) void agg_k(
    const unsigned short* __restrict__ hW,
    const float* __restrict__ b_edge,
    const int* __restrict__ cnt,
    const int* __restrict__ doff, const int* __restrict__ edst,
    float* __restrict__ agg, int N) {
  int tid = threadIdx.x;
  int lane = tid & 63, w = tid >> 6;
  int d = blockIdx.x * 4 + w;
  if (d >= N) return;

  int cv = 0;
  if (lane < TRELS) cv = cnt[d * TRELS + lane];
  float invl = (cv > 0) ? 1.0f / (float)cv : 0.0f;

  int start = doff[d], end = doff[d + 1];
  float ax = 0.f, ay = 0.f;
  for (int base = start; base < end; base += 64) {
    int key = 0;
    if (base + lane < end) key = edst[base + lane];
    int nchunk = end - base; if (nchunk > 64) nchunk = 64;
    int j = 0;
    for (; j + 4 <= nchunk; j += 4) {
      int k0 = __shfl(key, j, 64), k1 = __shfl(key, j + 1, 64);
      int k2 = __shfl(key, j + 2, 64), k3 = __shfl(key, j + 3, 64);
      float i0 = __shfl(invl, k0 & 15, 64), i1 = __shfl(invl, k1 & 15, 64);
      float i2 = __shfl(invl, k2 & 15, 64), i3 = __shfl(invl, k3 & 15, 64);
      ushort2 h0 = *reinterpret_cast<const ushort2*>(hW + ((size_t)(k0 & 15) * N + (k0 >> 4)) * D + lane * 2);
      ushort2 h1 = *reinterpret_cast<const ushort2*>(hW + ((size_t)(k1 & 15) * N + (k1 >> 4)) * D + lane * 2);
      ushort2 h2 = *reinterpret_cast<const ushort2*>(hW + ((size_t)(k2 & 15) * N + (k2 >> 4)) * D + lane * 2);
      ushort2 h3 = *reinterpret_cast<const ushort2*>(hW + ((size_t)(k3 & 15) * N + (k3 >> 4)) * D + lane * 2);
      ax += i0 * bf2f(h0.x); ay += i0 * bf2f(h0.y);
      ax += i1 * bf2f(h1.x); ay += i1 * bf2f(h1.y);
      ax += i2 * bf2f(h2.x); ay += i2 * bf2f(h2.y);
      ax += i3 * bf2f(h3.x); ay += i3 * bf2f(h3.y);
    }
    for (; j < nchunk; ++j) {
      int k = __shfl(key, j, 64);
      float inv = __shfl(invl, k & 15, 64);
      ushort2 hv = *reinterpret_cast<const ushort2*>(hW + ((size_t)(k & 15) * N + (k >> 4)) * D + lane * 2);
      ax += inv * bf2f(hv.x); ay += inv * bf2f(hv.y);
    }
  }
  // bias: sum of b_edge[et] over present etypes
#pragma unroll
  for (int et = 0; et < TRELS; ++et) {
    int c = __shfl(cv, et, 64);
    if (c > 0) {
      const float* bp = b_edge + et * D + lane * 2;
      ax += bp[0]; ay += bp[1];
    }
  }
  float2* op = reinterpret_cast<float2*>(agg + (size_t)d * D + lane * 2);
  *op = make_float2(ax, ay);
}

// ---------- node gather-GEMM: out = relu(feats@Wn[tn] + bn[tn] + agg) ----------
__global__ __launch_bounds__(256) void node_gemm_k(
    const unsigned short* __restrict__ featsbf,
    const unsigned short* __restrict__ WnT,
    const float* __restrict__ b_node,
    const int* __restrict__ nsorted, const int* __restrict__ misc,
    const float* __restrict__ agg,
    float* __restrict__ out) {
  __shared__ unsigned char Asm[128 * 264];
  __shared__ int sm_node[128];
  __shared__ int s_ntb[9];
  int tid = threadIdx.x;
  if (tid < 9) s_ntb[tid] = misc[9 + tid];
  __syncthreads();
  int bid = blockIdx.x;
  if (bid >= s_ntb[8]) return;
  int t = 0;
  while (bid >= s_ntb[t + 1]) ++t;
  int tile = bid - s_ntb[t];
  int noff_t = misc[t];
  int cntT = misc[t + 1] - noff_t;

  int lane = tid & 63, w = tid >> 6;
  int m = lane & 15, q = lane >> 4;
  int rw = (w & 1) * 64, cw = (w >> 1) * 64;

  const unsigned short* WB = WnT + t * (D * D);
  bf16x8 bfr[4][4];
#pragma unroll
  for (int ks = 0; ks < 4; ++ks)
#pragma unroll
    for (int j = 0; j < 4; ++j)
      bfr[ks][j] = *reinterpret_cast<const bf16x8*>(WB + (cw + j * 16 + m) * D + ks * 32 + q * 8);

  int r = tid >> 1, h = tid & 1;
  int gidx = tile * 128 + r;
  bool rv = gidx < cntT;
  int node = 0;
  if (rv) node = nsorted[noff_t + gidx];
  if (h == 0) sm_node[r] = rv ? node : -1;
  if (rv) {
    const u32x4* gp = reinterpret_cast<const u32x4*>(featsbf + (size_t)node * D);
#pragma unroll
    for (int cc = 0; cc < 8; ++cc) {
      int c = h * 8 + cc;
      *reinterpret_cast<u32x4*>(&Asm[r * 256 + ((c ^ (r & 7)) << 4)]) = gp[c];
    }
  }
  __syncthreads();

  f32x4 acc[4][4];
#pragma unroll
  for (int i = 0; i < 4; ++i)
#pragma unroll
    for (int j = 0; j < 4; ++j) acc[i][j] = (f32x4){0.f, 0.f, 0.f, 0.f};

#pragma unroll
  for (int ks = 0; ks < 4; ++ks) {
    bf16x8 a[4];
#pragma unroll
    for (int i = 0; i < 4; ++i) {
      int rr = rw + i * 16 + m;
      int c = ks * 4 + q;
      a[i] = *reinterpret_cast<const bf16x8*>(&Asm[rr * 256 + ((c ^ (rr & 7)) << 4)]);
    }
#pragma unroll
    for (int i = 0; i < 4; ++i)
#pragma unroll
      for (int j = 0; j < 4; ++j)
        acc[i][j] = __builtin_amdgcn_mfma_f32_16x16x32_bf16(a[i], bfr[ks][j], acc[i][j], 0, 0, 0);
  }

  // epilogue: two half-tile fp32 passes through LDS (pitch 132 floats = 528 B, 64 rows)
  const float* bnp = b_node + t * D;
  float* Cf = reinterpret_cast<float*>(Asm);
  __syncthreads();
#pragma unroll
  for (int half = 0; half < 2; ++half) {
    if ((w & 1) == half) {
#pragma unroll
      for (int i = 0; i < 4; ++i)
#pragma unroll
        for (int j = 0; j < 4; ++j)
#pragma unroll
          for (int reg = 0; reg < 4; ++reg) {
            int rl = i * 16 + q * 4 + reg;   // local row 0..63
            Cf[rl * 132 + cw + j * 16 + m] = acc[i][j][reg];
          }
    }
    __syncthreads();
#pragma unroll
    for (int cp = 0; cp < 8; ++cp) {
      int o = cp * 4096 + tid * 16;     // byte offset in 64x512B half tile
      int rl = o >> 9;
      int nd = sm_node[half * 64 + rl];
      if (nd >= 0) {
        int col = (o & 511) >> 2;
        f32x4 c = *reinterpret_cast<const f32x4*>((char*)Cf + rl * 528 + (o & 511));
        f32x4 a = *reinterpret_cast<const f32x4*>(agg + (size_t)nd * D + col);
        f32x4 b4 = *reinterpret_cast<const f32x4*>(bnp + col);
        f32x4 res;
#pragma unroll
        for (int z = 0; z < 4; ++z) res[z] = fmaxf(c[z] + a[z] + b4[z], 0.f);
        *reinterpret_cast<f32x4*>(out + (size_t)nd * D + col) = res;
      }
    }
    __syncthreads();
  }
}

static inline size_t align256(size_t x) { return (x + 255) & ~(size_t)255; }

extern "C" void kernel_launch(void* const* d_in, const int* in_sizes, int n_in,
                              void* d_out, int out_size, void* d_ws, size_t ws_size,
                              hipStream_t stream) {
  const float* feats  = (const float*)d_in[0];
  const float* W_edge = (const float*)d_in[1];
  const float* b_edge = (const float*)d_in[2];
  const float* W_node = (const float*)d_in[3];
  const float* b_node = (const float*)d_in[4];
  const int* src    = (const int*)d_in[5];
  const int* dst    = (const int*)d_in[6];
  const int* ntypes = (const int*)d_in[7];
  const int* etypes = (const int*)d_in[8];
  int N = in_sizes[0] / D;   // 50000
  int E = in_sizes[5];       // 640000

  char* ws = (char*)d_ws;
  size_t o_cnt  = 0;
  size_t o_misc = align256(o_cnt + (size_t)N * TRELS * 4);
  size_t o_su   = align256(o_misc + 512);
  size_t zend   = align256(o_su + (size_t)N * 4);
  size_t o_doff = zend;
  size_t o_dcur = align256(o_doff + (size_t)(N + 1) * 4);
  size_t o_edst = align256(o_dcur + (size_t)N * 4);
  size_t o_ns   = align256(o_edst + (size_t)E * 4);
  size_t o_fb   = align256(o_ns + (size_t)N * 4);
  size_t o_we   = align256(o_fb + (size_t)N * D * 2);
  size_t o_wn   = align256(o_we + (size_t)TRELS * D * D * 2);
  size_t o_agg  = align256(o_wn + (size_t)NTYPES * D * D * 2);
  size_t o_hw   = align256(o_agg + (size_t)N * D * 4);

  int* cnt = (int*)(ws + o_cnt);
  int* misc = (int*)(ws + o_misc);
  int* srcuse = (int*)(ws + o_su);
  int* doff = (int*)(ws + o_doff);
  int* dcur = (int*)(ws + o_dcur);
  int* edst = (int*)(ws + o_edst);
  int* nsorted = (int*)(ws + o_ns);
  unsigned short* featsbf = (unsigned short*)(ws + o_fb);
  unsigned short* WeT = (unsigned short*)(ws + o_we);
  unsigned short* WnT = (unsigned short*)(ws + o_wn);
  float* agg = (float*)(ws + o_agg);
  unsigned short* hW = (unsigned short*)(ws + o_hw);
  int* bsum = misc + 64;

  (void)hipMemsetAsync(ws, 0, zend, stream);

  int nfeat = N * D;
  int ptot = nfeat + TRELS * D * D + NTYPES * D * D;
  prep_k<<<(ptot + 255) / 256, 256, 0, stream>>>(feats, W_edge, W_node, featsbf, WeT, WnT, nfeat);

  int hgrid = ((E > N ? E : N) + 255) / 256;
  hist_k<<<hgrid, 256, 0, stream>>>(src, dst, etypes, ntypes, E, N, cnt, misc + 26, srcuse);

  int nb = (N + 1023) / 1024;
  scan1_k<<<nb, 256, 0, stream>>>(cnt, doff, bsum, N);
  scan2_k<<<1, 64, 0, stream>>>(misc, bsum, nb);
  scan3_k<<<nb, 256, 0, stream>>>(doff, dcur, bsum, N, E);

  scatter_k<<<hgrid, 256, 0, stream>>>(src, dst, etypes, ntypes, E, N, misc, dcur, edst, nsorted);

  int mtiles = (N + 127) / 128;
  hw_gemm_k<<<mtiles * 16, 256, 0, stream>>>(featsbf, WeT, srcuse, hW, N, mtiles);

  agg_k<<<(N + 3) / 4, 256, 0, stream>>>(hW, b_edge, cnt, doff, edst, agg, N);

  int ngrid = mtiles + NTYPES;
  node_gemm_k<<<ngrid, 256, 0, stream>>>(featsbf, WnT, b_node, nsorted, misc, agg, (float*)d_out);
}